// Round 5
// baseline (222.570 us; speedup 1.0000x reference)
//
#include <hip/hip_runtime.h>

#define NPIX 49152   // B*H*W = 1*192*256
#define H_ 192
#define W_ 256
#define TPB 64       // tokens per chain block (64 tokens x 4 lanes = 256 thr)

// W-tile bank swizzle: col' = col + (col>>5)*4
#define WSWZ(c) ((c) + (((c) >> 5) << 2))

// ---------------------------------------------------------------------------
// both weight transposes (32 blocks) + zero binning counters (block 0)
// ---------------------------------------------------------------------------
__global__ __launch_bounds__(256) void wtrans2_k(const float* __restrict__ Wa,
    float* __restrict__ WTa, const float* __restrict__ Wb,
    float* __restrict__ WTb, int* __restrict__ S) {
  const int b = blockIdx.x;
  const float* __restrict__ W = (b < 16) ? Wa : Wb;
  float* __restrict__ WT = (b < 16) ? WTa : WTb;
  const int bb = b & 15;
  __shared__ float tile[32][33];
  const int bx = bb & 3, by = bb >> 2;
  const int c = threadIdx.x & 31, r0 = threadIdx.x >> 5;
#pragma unroll
  for (int j = 0; j < 4; ++j) {
    const int r = r0 + j * 8;
    tile[r][c] = W[(by * 32 + r) * 128 + bx * 32 + c];
  }
  __syncthreads();
#pragma unroll
  for (int j = 0; j < 4; ++j) {
    const int r = r0 + j * 8;
    WT[(bx * 32 + r) * 128 + by * 32 + c] = tile[c][r];
  }
  if (b == 0) {
    const int t = threadIdx.x;
    if (t < 32) S[t] = 0;        // cnt1 + cur1
    S[1088 + t] = 0;             // cnt2
    S[1344 + t] = 0;             // cur2
  }
}

// ---------------------------------------------------------------------------
// conv 128->128 as register-blocked GEMM (unchanged from round 4).
// ---------------------------------------------------------------------------
template<bool ACT>
__global__ __launch_bounds__(128) void conv128_v3(const float* __restrict__ X,
    const float* __restrict__ WT, const float* __restrict__ Bv,
    float* __restrict__ Y) {
  __shared__ float xb[2][16][32];
  __shared__ float wb[2][16][140];
  const int t = threadIdx.x;
  const int p0 = blockIdx.x * 32;
  const int to = t >> 3;
  const int tp = t & 7;
  const int wcol = WSWZ(to * 8);

  float acc[8][4];
#pragma unroll
  for (int i = 0; i < 8; ++i) {
    const float b = Bv[to * 8 + i];
#pragma unroll
    for (int j = 0; j < 4; ++j) acc[i][j] = b;
  }

  {
    const int k = t >> 3, c = (t & 7) * 4;
    *(float4*)(&xb[0][k][c]) = *(const float4*)(X + k * NPIX + p0 + c);
  }
#pragma unroll
  for (int j = 0; j < 4; ++j) {
    const int idx = t + j * 128, k = idx >> 5, c = (idx & 31) * 4;
    *(float4*)(&wb[0][k][WSWZ(c)]) = *(const float4*)(WT + k * 128 + c);
  }
  __syncthreads();

  for (int ch = 0; ch < 8; ++ch) {
    const int cur = ch & 1, nxt = cur ^ 1;
    float4 xs, ws[4];
    const int k1 = (ch + 1) * 16;
    if (ch < 7) {
      {
        const int k = t >> 3, c = (t & 7) * 4;
        xs = *(const float4*)(X + (k1 + k) * NPIX + p0 + c);
      }
#pragma unroll
      for (int j = 0; j < 4; ++j) {
        const int idx = t + j * 128, k = idx >> 5, c = (idx & 31) * 4;
        ws[j] = *(const float4*)(WT + (k1 + k) * 128 + c);
      }
    }
#pragma unroll
    for (int k = 0; k < 16; ++k) {
      float xv[4], wv[8];
      *(float4*)&xv[0] = *(const float4*)(&xb[cur][k][tp * 4]);
      *(float4*)&wv[0] = *(const float4*)(&wb[cur][k][wcol]);
      *(float4*)&wv[4] = *(const float4*)(&wb[cur][k][wcol + 4]);
#pragma unroll
      for (int i = 0; i < 8; ++i)
#pragma unroll
        for (int j = 0; j < 4; ++j)
          acc[i][j] = fmaf(wv[i], xv[j], acc[i][j]);
    }
    __syncthreads();
    if (ch < 7) {
      {
        const int k = t >> 3, c = (t & 7) * 4;
        *(float4*)(&xb[nxt][k][c]) = xs;
      }
#pragma unroll
      for (int j = 0; j < 4; ++j) {
        const int idx = t + j * 128, k = idx >> 5, c = (idx & 31) * 4;
        *(float4*)(&wb[nxt][k][WSWZ(c)]) = ws[j];
      }
      __syncthreads();
    }
  }

#pragma unroll
  for (int i = 0; i < 8; ++i) {
    float4 v;
    float* pv = (float*)&v;
#pragma unroll
    for (int j = 0; j < 4; ++j) {
      float x = acc[i][j];
      if (ACT) x = x > 0.f ? x : 0.01f * x;
      pv[j] = x;
    }
    *(float4*)(Y + (to * 8 + i) * NPIX + p0 + tp * 4) = v;
  }
}

// ---------------------------------------------------------------------------
// conv 128->17 + argmax + mask + fused inds1 histogram (unchanged).
// ---------------------------------------------------------------------------
__global__ __launch_bounds__(256) void conv17_k(const float* __restrict__ X,
    const float* __restrict__ W, const float* __restrict__ Bv,
    unsigned char* __restrict__ inds1, float* __restrict__ mask_out,
    int* __restrict__ cnt1) {
  __shared__ int lh[16];
  const int t = threadIdx.x;
  if (t < 16) lh[t] = 0;
  __syncthreads();
  const int p = blockIdx.x * 256 + t;
  float acc[17];
#pragma unroll
  for (int o = 0; o < 17; ++o) acc[o] = Bv[o];
  for (int k0 = 0; k0 < 128; k0 += 8) {
    float xv[8];
#pragma unroll
    for (int kk = 0; kk < 8; ++kk) xv[kk] = X[(k0 + kk) * NPIX + p];
#pragma unroll
    for (int o = 0; o < 17; ++o) {
#pragma unroll
      for (int kk = 0; kk < 8; ++kk)
        acc[o] = fmaf(xv[kk], W[o * 128 + k0 + kk], acc[o]);
    }
  }
  int am = 0;
  float bv = acc[0];
#pragma unroll
  for (int o = 1; o < 16; ++o) {
    if (acc[o] > bv) { bv = acc[o]; am = o; }
  }
  inds1[p] = (unsigned char)am;
  const float m = acc[16];
  mask_out[p] = m > 0.f ? m : 0.01f * m;
  atomicAdd(&lh[am], 1);
  __syncthreads();
  if (t < 16 && lh[t] > 0) atomicAdd(&cnt1[t], lh[t]);
}

// ---------------------------------------------------------------------------
// transpose x[k][h][w] -> xt[(w*H+h)*128 + k]
// ---------------------------------------------------------------------------
__global__ __launch_bounds__(256) void transpose_k(const float* __restrict__ X,
                                                   float* __restrict__ xt) {
  __shared__ float tile[32][33];
  const int w0 = (blockIdx.x & 7) * 32;
  const int k0 = ((blockIdx.x >> 3) & 3) * 32;
  const int h  = blockIdx.x >> 5;
  const int t = threadIdx.x;
  const int c = t & 31, rr = t >> 5;
#pragma unroll
  for (int j = 0; j < 4; ++j) {
    const int k = rr + j * 8;
    tile[k][c] = X[(k0 + k) * NPIX + h * W_ + w0 + c];
  }
  __syncthreads();
#pragma unroll
  for (int j = 0; j < 4; ++j) {
    const int w = rr + j * 8;
    xt[((w0 + w) * H_ + h) * 128 + k0 + c] = tile[c][w];
  }
}

// parallel scan + descriptor emit
template<int NB>
__global__ __launch_bounds__(256) void scan_desc_k(const int* __restrict__ cnt,
    int* __restrict__ off, int* __restrict__ desc, int* __restrict__ ndesc) {
  const int t = threadIdx.x;
  const int lane = t & 63, wvi = t >> 6;
  __shared__ int wsumC[4], wsumD[4];
  const int c = (t < NB) ? cnt[t] : 0;
  const int nb = (c + TPB - 1) / TPB;
  int ic = c, id = nb;
  for (int d = 1; d < 64; d <<= 1) {
    const int uc = __shfl_up(ic, d, 64);
    const int ud = __shfl_up(id, d, 64);
    if (lane >= d) { ic += uc; id += ud; }
  }
  if (lane == 63) { wsumC[wvi] = ic; wsumD[wvi] = id; }
  __syncthreads();
  int bc = 0, bd = 0;
#pragma unroll
  for (int w2 = 0; w2 < 4; ++w2) {
    if (w2 < wvi) { bc += wsumC[w2]; bd += wsumD[w2]; }
  }
  ic += bc; id += bd;
  if (t < NB) {
    off[t] = ic - c;
    const int db = id - nb;
    for (int j = 0; j < nb; ++j) desc[db + j] = (t << 12) | j;
  }
  if (t == NB - 1) *ndesc = id;
}

// two-level scatter
template<typename T>
__global__ __launch_bounds__(256) void scatter_k(const T* __restrict__ bins,
    const int* __restrict__ off, int* __restrict__ cursor,
    int* __restrict__ ord, int nbins) {
  __shared__ int lhist[256], lbase[256], lcur[256];
  const int t = threadIdx.x;
  const int n = blockIdx.x * 256 + t;
  if (t < nbins) { lhist[t] = 0; lcur[t] = 0; }
  __syncthreads();
  const int b = (int)bins[n];
  atomicAdd(&lhist[b], 1);
  __syncthreads();
  if (t < nbins && lhist[t] > 0) lbase[t] = atomicAdd(&cursor[t], lhist[t]);
  __syncthreads();
  const int r = atomicAdd(&lcur[b], 1);
  ord[off[b] + lbase[b] + r] = n;
}

// ---------------------------------------------------------------------------
// chain1 v2: 4 lanes per token, split by OUTPUT channel. Each output remains
// one bias-then-k-ascending FMA chain -> logits bitwise identical to v1.
// Activations move between layers via __shfl within the 4-lane group.
// ---------------------------------------------------------------------------
__global__ __launch_bounds__(256) void chain1_k(const float* __restrict__ xt,
    const int* __restrict__ ord1, const int* __restrict__ off1,
    const int* __restrict__ cnt1, const int* __restrict__ desc1,
    const int* __restrict__ nd1,
    const float* __restrict__ wc21, const float* __restrict__ bc21,
    const float* __restrict__ wc22, const float* __restrict__ bc22,
    const float* __restrict__ wc23, const float* __restrict__ bc23,
    int* __restrict__ e12a, int* __restrict__ cnt2) {
  if ((int)blockIdx.x >= *nd1) return;
  __shared__ int lh[16];
  const int t = threadIdx.x;
  if (t < 16) lh[t] = 0;
  __syncthreads();
  const int tg = t >> 2, sub = t & 3;
  const int l0 = (t & 63) & ~3;          // group base lane within wave
  const int de = desc1[blockIdx.x];
  const int e = de >> 12, chunk = de & 0xFFF;
  const int cnt = cnt1[e];
  const int pos = chunk * TPB + tg;
  const bool valid = pos < cnt;
  const int n = valid ? ord1[off1[e] + pos] : 0;
  const float* __restrict__ xr = xt + n * 128;

  // L1: outputs sub*8..sub*8+7 over all 128 k
  const float* __restrict__ W1 = wc21 + e * 4096 + sub * 8;
  const float* __restrict__ B1 = bc21 + e * 32 + sub * 8;
  float a[8];
#pragma unroll
  for (int o = 0; o < 8; ++o) a[o] = B1[o];
  for (int k = 0; k < 128; k += 4) {
    const float4 xv = *(const float4*)(xr + k);
    const float xs[4] = {xv.x, xv.y, xv.z, xv.w};
#pragma unroll
    for (int kk = 0; kk < 4; ++kk)
#pragma unroll
      for (int o = 0; o < 8; ++o)
        a[o] = fmaf(xs[kk], W1[(k + kk) * 32 + o], a[o]);
  }
#pragma unroll
  for (int o = 0; o < 8; ++o) a[o] = a[o] > 0.f ? a[o] : 0.01f * a[o];

  // L2: outputs sub*8..sub*8+7 over 32 inputs (shfl from group)
  const float* __restrict__ W2 = wc22 + e * 1024 + sub * 8;
  const float* __restrict__ B2 = bc22 + e * 32 + sub * 8;
  float b[8];
#pragma unroll
  for (int o = 0; o < 8; ++o) b[o] = B2[o];
#pragma unroll
  for (int i = 0; i < 32; ++i) {
    const float hv = __shfl(a[i & 7], l0 + (i >> 3), 64);
#pragma unroll
    for (int o = 0; o < 8; ++o)
      b[o] = fmaf(hv, W2[i * 32 + o], b[o]);
  }
#pragma unroll
  for (int o = 0; o < 8; ++o) b[o] = b[o] > 0.f ? b[o] : 0.01f * b[o];

  // L3: outputs sub*4..sub*4+3 (16 logits total)
  const float* __restrict__ W3 = wc23 + e * 512 + sub * 4;
  const float* __restrict__ B3 = bc23 + e * 16 + sub * 4;
  float s[4];
#pragma unroll
  for (int j = 0; j < 4; ++j) s[j] = B3[j];
#pragma unroll
  for (int i = 0; i < 32; ++i) {
    const float hv = __shfl(b[i & 7], l0 + (i >> 3), 64);
#pragma unroll
    for (int j = 0; j < 4; ++j)
      s[j] = fmaf(hv, W3[i * 16 + j], s[j]);
  }

  // argmax over 16: local first-max-wins, then min-index-of-max combine
  float bv = s[0];
  int bi = sub * 4;
#pragma unroll
  for (int j = 1; j < 4; ++j) {
    if (s[j] > bv) { bv = s[j]; bi = sub * 4 + j; }
  }
#pragma unroll
  for (int d = 1; d < 4; d <<= 1) {
    const float ov = __shfl_xor(bv, d, 64);
    const int oi = __shfl_xor(bi, d, 64);
    if (ov > bv || (ov == bv && oi < bi)) { bv = ov; bi = oi; }
  }
  const int e12 = e * 16 + bi;
  if (valid && sub == 0) {
    e12a[n] = e12;
    atomicAdd(&lh[bi], 1);
  }
  __syncthreads();
  if (t < 16 && lh[t] > 0)
    atomicAdd(&cnt2[e * 16 + t], lh[t]);
}

// ---------------------------------------------------------------------------
// chain2 v2: same 4-lane-per-token structure. Writes out[n].
// ---------------------------------------------------------------------------
__global__ __launch_bounds__(256) void chain2_k(const float* __restrict__ xt,
    const int* __restrict__ ord2, const int* __restrict__ off2,
    const int* __restrict__ cnt2, const int* __restrict__ desc2,
    const int* __restrict__ nd2,
    const float* __restrict__ wr11, const float* __restrict__ br11,
    const float* __restrict__ wr12, const float* __restrict__ br12,
    const float* __restrict__ wr13, const float* __restrict__ br13,
    float* __restrict__ out) {
  if ((int)blockIdx.x >= *nd2) return;
  const int t = threadIdx.x;
  const int tg = t >> 2, sub = t & 3;
  const int l0 = (t & 63) & ~3;
  const int de = desc2[blockIdx.x];
  const int e12 = de >> 12, chunk = de & 0xFFF;
  const int cnt = cnt2[e12];
  const int pos = chunk * TPB + tg;
  const bool valid = pos < cnt;
  const int n = valid ? ord2[off2[e12] + pos] : 0;
  const float* __restrict__ xr = xt + n * 128;

  // L1: 128 -> 32, lane owns 8 outputs
  const float* __restrict__ W1 = wr11 + e12 * 4096 + sub * 8;
  const float* __restrict__ B1 = br11 + e12 * 32 + sub * 8;
  float a[8];
#pragma unroll
  for (int o = 0; o < 8; ++o) a[o] = B1[o];
  for (int k = 0; k < 128; k += 4) {
    const float4 xv = *(const float4*)(xr + k);
    const float xs[4] = {xv.x, xv.y, xv.z, xv.w};
#pragma unroll
    for (int kk = 0; kk < 4; ++kk)
#pragma unroll
      for (int o = 0; o < 8; ++o)
        a[o] = fmaf(xs[kk], W1[(k + kk) * 32 + o], a[o]);
  }
#pragma unroll
  for (int o = 0; o < 8; ++o) a[o] = a[o] > 0.f ? a[o] : 0.01f * a[o];

  // L2: 32 -> 16, lane owns 4 outputs
  const float* __restrict__ W2 = wr12 + e12 * 512 + sub * 4;
  const float* __restrict__ B2 = br12 + e12 * 16 + sub * 4;
  float s[4];
#pragma unroll
  for (int j = 0; j < 4; ++j) s[j] = B2[j];
#pragma unroll
  for (int i = 0; i < 32; ++i) {
    const float hv = __shfl(a[i & 7], l0 + (i >> 3), 64);
#pragma unroll
    for (int j = 0; j < 4; ++j)
      s[j] = fmaf(hv, W2[i * 16 + j], s[j]);
  }
#pragma unroll
  for (int j = 0; j < 4; ++j) s[j] = s[j] > 0.f ? s[j] : 0.01f * s[j];

  // L3: 16 -> 1 (i ascending, bitwise same as v1); all lanes redundant
  float r = br13[e12];
  const float* __restrict__ W3 = wr13 + e12 * 16;
#pragma unroll
  for (int i = 0; i < 16; ++i) {
    const float hv = __shfl(s[i & 3], l0 + (i >> 2), 64);
    r = fmaf(hv, W3[i], r);
  }

  if (valid && sub == 0) out[n] = ((float)e12 + r) * (1.0f / 256.0f);
}

// ---------------------------------------------------------------------------
extern "C" void kernel_launch(void* const* d_in, const int* in_sizes, int n_in,
                              void* d_out, int out_size, void* d_ws,
                              size_t ws_size, hipStream_t stream) {
  const float* x_in  = (const float*)d_in[0];
  const float* w_c11 = (const float*)d_in[1];
  const float* b_c11 = (const float*)d_in[2];
  const float* w_c12 = (const float*)d_in[3];
  const float* b_c12 = (const float*)d_in[4];
  const float* w_c13 = (const float*)d_in[5];
  const float* b_c13 = (const float*)d_in[6];
  const float* w_c21 = (const float*)d_in[7];
  const float* b_c21 = (const float*)d_in[8];
  const float* w_c22 = (const float*)d_in[9];
  const float* b_c22 = (const float*)d_in[10];
  const float* w_c23 = (const float*)d_in[11];
  const float* b_c23 = (const float*)d_in[12];
  const float* w_r11 = (const float*)d_in[13];
  const float* b_r11 = (const float*)d_in[14];
  const float* w_r12 = (const float*)d_in[15];
  const float* b_r12 = (const float*)d_in[16];
  const float* w_r13 = (const float*)d_in[17];
  const float* b_r13 = (const float*)d_in[18];

  float* out = (float*)d_out;   // [0..N): x_real (token order), [N..2N): mask

  float* R0 = (float*)d_ws;
  float* R1 = R0 + 128 * NPIX;
  float* R2 = R1 + 128 * NPIX;

  float* y1 = R0;
  float* y2 = R1;
  float* xt = R0;
  unsigned char* inds1 = (unsigned char*)R2;   // N bytes
  float* wT1 = R2 + 12288;
  float* wT2 = wT1 + 16384;
  int* S = (int*)R2 + 45056;

  int* cnt1  = S;            // 16
  int* cur1  = S + 16;       // 16
  int* off1  = S + 32;       // 16
  int* nd1   = S + 48;       // 1 (+pad)
  int* desc1 = S + 64;       // 1024
  int* cnt2  = S + 1088;     // 256
  int* cur2  = S + 1344;     // 256
  int* off2  = S + 1600;     // 256
  int* nd2   = S + 1856;     // 1 (+pad)
  int* desc2 = S + 1872;     // 1024

  int* ib   = (int*)R1;
  int* ord1 = ib;            // N
  int* ord2 = ib + NPIX;     // N
  int* e12a = ib + 2 * NPIX; // N

  wtrans2_k<<<32, 256, 0, stream>>>(w_c11, wT1, w_c12, wT2, S);
  conv128_v3<true><<<NPIX / 32, 128, 0, stream>>>(x_in, wT1, b_c11, y1);
  conv128_v3<true><<<NPIX / 32, 128, 0, stream>>>(y1, wT2, b_c12, y2);
  transpose_k<<<192 * 32, 256, 0, stream>>>(x_in, xt);
  conv17_k<<<NPIX / 256, 256, 0, stream>>>(y2, w_c13, b_c13, inds1,
                                           out + NPIX, cnt1);
  scan_desc_k<16><<<1, 256, 0, stream>>>(cnt1, off1, desc1, nd1);
  scatter_k<unsigned char><<<NPIX / 256, 256, 0, stream>>>(inds1, off1, cur1,
                                                           ord1, 16);
  chain1_k<<<NPIX / TPB + 16, 256, 0, stream>>>(xt, ord1, off1, cnt1, desc1,
      nd1, w_c21, b_c21, w_c22, b_c22, w_c23, b_c23, e12a, cnt2);
  scan_desc_k<256><<<1, 256, 0, stream>>>(cnt2, off2, desc2, nd2);
  scatter_k<int><<<NPIX / 256, 256, 0, stream>>>(e12a, off2, cur2, ord2, 256);
  chain2_k<<<NPIX / TPB + 256, 256, 0, stream>>>(xt, ord2, off2, cnt2, desc2,
      nd2, w_r11, b_r11, w_r12, b_r12, w_r13, b_r13, out);
}